// Round 1
// baseline (16308.662 us; speedup 1.0000x reference)
//
#include <hip/hip_runtime.h>

#define BATCHN 256
#define SEQL   512
#define HID    2048
#define NCLS   10

typedef _Float16 f16x8 __attribute__((ext_vector_type(8)));
typedef _Float16 f16x4 __attribute__((ext_vector_type(4)));
typedef float    f32x4 __attribute__((ext_vector_type(4)));

__device__ __forceinline__ float fast_tanh(float v) {
    float e = __expf(2.0f * v);
    return 1.0f - 2.0f / (e + 1.0f);
}

// whh fp32 -> fp16 (row-major [j][k] preserved)
__global__ void convert_w_kernel(const float* __restrict__ w, _Float16* __restrict__ o) {
    const int i = (blockIdx.x * 256 + threadIdx.x) * 4;
    const float4 v = *(const float4*)(w + i);
    f16x4 h;
    h[0] = (_Float16)v.x; h[1] = (_Float16)v.y;
    h[2] = (_Float16)v.z; h[3] = (_Float16)v.w;
    *(f16x4*)(o + i) = h;
}

// 32-WG group barrier: monotonic counter, release(wbl2) before arrive,
// relaxed spin, acquire(inv) after. Correct for any WG->XCD placement.
__device__ __forceinline__ void group_barrier(unsigned* gctr, unsigned bi) {
    __syncthreads();   // all waves' h-stores drained (s_waitcnt vmcnt(0) before s_barrier)
    if (threadIdx.x == 0) {
        __builtin_amdgcn_fence(__ATOMIC_RELEASE, "agent");
        atomicAdd(gctr, 1u);
        const unsigned target = 32u * bi;
        while (__hip_atomic_load(gctr, __ATOMIC_RELAXED, __HIP_MEMORY_SCOPE_AGENT) < target)
            __builtin_amdgcn_s_sleep(1);
    }
    __syncthreads();
    __builtin_amdgcn_fence(__ATOMIC_ACQUIRE, "agent");
}

__global__ void __launch_bounds__(256, 1)
rnn_main(const float* __restrict__ x, const float* __restrict__ whx,
         const _Float16* __restrict__ W, const float* __restrict__ bh,
         const float* __restrict__ wph, const float* __restrict__ bp,
         _Float16* __restrict__ h0, _Float16* __restrict__ h1,
         unsigned* __restrict__ ctr, float* __restrict__ out)
{
    __shared__ uint4 lds4[8192];          // 128 KiB: pinned W cols [colbase, colbase+32)
    char* lds = (char*)lds4;

    const int tid = threadIdx.x;
    const int wg  = blockIdx.x;
    const int g   = wg & 7;               // group (XCD if round-robin dispatch)
    const int m   = wg >> 3;              // member 0..31
    const int rowbase = g * 32;           // group owns batch rows [rowbase, +32)
    const int colbase = m * 64;           // member owns hidden cols [colbase, +64)
    const int lane = tid & 63;
    const int w   = tid >> 6;             // wave 0..3
    const int wm  = w & 1;                // M-half
    const int wn  = w >> 1;               // N-half: 0 -> LDS-pinned cols, 1 -> streamed cols
    unsigned* gctr = ctr + g * 64;        // 256B-padded per-group counter

    // ---- pin W cols [colbase, colbase+32) into LDS, XOR-swizzled 16B chunks ----
    for (int i = tid; i < 32 * 256; i += 256) {
        const int cl = i >> 8;            // local col 0..31
        const int kc = i & 255;           // 16B chunk (k/8)
        const uint4 v = *(const uint4*)(W + (size_t)(colbase + cl) * HID + kc * 8);
        *(uint4*)(lds + cl * 4096 + ((kc * 16) ^ ((cl & 7) << 4))) = v;
    }

    // ---- step 0 (t=0): h = tanh(x[:,0]*whx + bh), no GEMM needed (h_prev = 0) ----
    for (int i = tid; i < 32 * 64; i += 256) {
        const int r = i >> 6, c = i & 63;
        const int b = rowbase + r, j = colbase + c;
        h0[(size_t)b * HID + j] = (_Float16)fast_tanh(x[(size_t)b * SEQL] * whx[j] + bh[j]);
    }

    group_barrier(gctr, 1u);

    // hoisted per-lane epilogue constants (C/D layout: col=lane&15, row=(lane>>4)*4+r)
    const int c0 = colbase + wn * 32 + (lane & 15);
    const int c1 = c0 + 16;
    const float wx0 = whx[c0], wx1 = whx[c1];
    const float bb0 = bh[c0],  bb1 = bh[c1];
    const int arow = rowbase + wm * 16 + (lane & 15);   // A-operand row
    const int kq   = (lane >> 4) * 8;                   // per-lane k offset (8 halves)

    for (int t = 1; t < SEQL; ++t) {
        const _Float16* hs = (t & 1) ? h0 : h1;
        _Float16*       hd = (t & 1) ? h1 : h0;
        const _Float16* ap = hs + (size_t)arow * HID + kq;

        f32x4 a00 = {0.f,0.f,0.f,0.f}, a01 = a00, a10 = a00, a11 = a00;

        if (wn == 0) {
            // B from pinned LDS (cols colbase..colbase+32)
            const char* b0 = lds + (lane & 15) * 4096;
            const char* b1 = b0 + 16 * 4096;
            const int sw = (lane & 7) << 4;
            #pragma unroll 4
            for (int kk = 0; kk < HID; kk += 64) {
                const f16x8 a0 = *(const f16x8*)(ap + kk);
                const f16x8 a1 = *(const f16x8*)(ap + kk + 32);
                const int kb0 = (kk + kq) * 2;
                const int kb1 = kb0 + 64;
                const f16x8 p00 = *(const f16x8*)(b0 + (kb0 ^ sw));
                const f16x8 p10 = *(const f16x8*)(b1 + (kb0 ^ sw));
                const f16x8 p01 = *(const f16x8*)(b0 + (kb1 ^ sw));
                const f16x8 p11 = *(const f16x8*)(b1 + (kb1 ^ sw));
                a00 = __builtin_amdgcn_mfma_f32_16x16x32_f16(a0, p00, a00, 0, 0, 0);
                a10 = __builtin_amdgcn_mfma_f32_16x16x32_f16(a0, p10, a10, 0, 0, 0);
                a01 = __builtin_amdgcn_mfma_f32_16x16x32_f16(a1, p01, a01, 0, 0, 0);
                a11 = __builtin_amdgcn_mfma_f32_16x16x32_f16(a1, p11, a11, 0, 0, 0);
            }
        } else {
            // B streamed from global W (cols colbase+32..colbase+64), L2-resident
            const _Float16* q0 = W + (size_t)(colbase + 32 + (lane & 15)) * HID + kq;
            const _Float16* q1 = q0 + (size_t)16 * HID;
            #pragma unroll 4
            for (int kk = 0; kk < HID; kk += 64) {
                const f16x8 a0 = *(const f16x8*)(ap + kk);
                const f16x8 a1 = *(const f16x8*)(ap + kk + 32);
                const f16x8 p00 = *(const f16x8*)(q0 + kk);
                const f16x8 p10 = *(const f16x8*)(q1 + kk);
                const f16x8 p01 = *(const f16x8*)(q0 + kk + 32);
                const f16x8 p11 = *(const f16x8*)(q1 + kk + 32);
                a00 = __builtin_amdgcn_mfma_f32_16x16x32_f16(a0, p00, a00, 0, 0, 0);
                a10 = __builtin_amdgcn_mfma_f32_16x16x32_f16(a0, p10, a10, 0, 0, 0);
                a01 = __builtin_amdgcn_mfma_f32_16x16x32_f16(a1, p01, a01, 0, 0, 0);
                a11 = __builtin_amdgcn_mfma_f32_16x16x32_f16(a1, p11, a11, 0, 0, 0);
            }
        }

        // epilogue: sum K-parity accumulators, add x_t*whx + bh, tanh, store fp16
        const f32x4 s0 = a00 + a01;
        const f32x4 s1 = a10 + a11;
        const int rb = rowbase + wm * 16 + (lane >> 4) * 4;
        #pragma unroll
        for (int r = 0; r < 4; ++r) {
            const int br = rb + r;
            const float xv = x[(size_t)br * SEQL + t];
            hd[(size_t)br * HID + c0] = (_Float16)fast_tanh(s0[r] + xv * wx0 + bb0);
            hd[(size_t)br * HID + c1] = (_Float16)fast_tanh(s1[r] + xv * wx1 + bb1);
        }

        group_barrier(gctr, (unsigned)(t + 1));
    }

    // ---- projection: p = h_last @ wph.T + bp   (h_last in h1; member m -> local row m) ----
    const int brow = rowbase + m;
    const _Float16* hp = h1 + (size_t)brow * HID + lane * 32;
    for (int c = w; c < NCLS; c += 4) {
        const float* wp = wph + (size_t)c * HID + lane * 32;
        float s = 0.f;
        #pragma unroll
        for (int i = 0; i < 32; ++i) s += (float)hp[i] * wp[i];
        #pragma unroll
        for (int off = 32; off >= 1; off >>= 1) s += __shfl_xor(s, off, 64);
        if (lane == 0) out[brow * NCLS + c] = s + bp[c];
    }
}

extern "C" void kernel_launch(void* const* d_in, const int* in_sizes, int n_in,
                              void* d_out, int out_size, void* d_ws, size_t ws_size,
                              hipStream_t stream) {
    const float* x   = (const float*)d_in[0];
    const float* whx = (const float*)d_in[1];
    const float* whh = (const float*)d_in[2];
    const float* bh  = (const float*)d_in[3];
    const float* wph = (const float*)d_in[4];
    const float* bp  = (const float*)d_in[5];
    float* out = (float*)d_out;

    char* ws = (char*)d_ws;
    _Float16* W16 = (_Float16*)ws;                        // 8 MiB  whh in fp16
    _Float16* h0  = (_Float16*)(ws + (size_t)(8u << 20)); // 1 MiB  h buffer A
    _Float16* h1  = (_Float16*)(ws + (size_t)(9u << 20)); // 1 MiB  h buffer B
    unsigned* ctr = (unsigned*)(ws + (size_t)(10u << 20)); // 2 KiB  group barrier counters

    hipMemsetAsync(ctr, 0, 8 * 64 * sizeof(unsigned), stream);
    convert_w_kernel<<<dim3(4096), dim3(256), 0, stream>>>(whh, W16);

    void* args[] = { (void*)&x, (void*)&whx, (void*)&W16, (void*)&bh, (void*)&wph,
                     (void*)&bp, (void*)&h0, (void*)&h1, (void*)&ctr, (void*)&out };
    hipLaunchCooperativeKernel((const void*)rnn_main, dim3(256), dim3(256),
                               args, 0, stream);
}

// Round 2
// 10133.395 us; speedup vs baseline: 1.6094x; 1.6094x over previous
//
#include <hip/hip_runtime.h>

#define BATCHN 256
#define SEQL   512
#define HID    2048
#define NCLS   10

typedef _Float16 f16x8 __attribute__((ext_vector_type(8)));
typedef _Float16 f16x4 __attribute__((ext_vector_type(4)));
typedef float    f32x4 __attribute__((ext_vector_type(4)));

__device__ __forceinline__ float fast_tanh(float v) {
    float e = __expf(2.0f * v);
    return 1.0f - 2.0f / (e + 1.0f);
}

// whh fp32 -> fp16 (row-major [j][k] preserved)
__global__ void convert_w_kernel(const float* __restrict__ w, _Float16* __restrict__ o) {
    const int i = (blockIdx.x * 256 + threadIdx.x) * 4;
    const float4 v = *(const float4*)(w + i);
    f16x4 h;
    h[0] = (_Float16)v.x; h[1] = (_Float16)v.y;
    h[2] = (_Float16)v.z; h[3] = (_Float16)v.w;
    *(f16x4*)(o + i) = h;
}

// XCD-local 32-WG barrier. All members are physically on one XCD (membership
// derived from HW_REG_XCC_ID), so coherence point is the shared per-XCD L2:
//   release: __syncthreads (per-wave s_waitcnt vmcnt(0); L1 is write-through -> stores in L2)
//   arrive:  workgroup-scope atomicAdd (global_atomic_add, executes at local L2)
//   spin:    agent-scope relaxed load (sc0: bypass L1, hit local L2)
//   acquire: buffer_inv sc0 (invalidate this CU's L1 only; L2 untouched)
__device__ __forceinline__ void group_barrier(unsigned* gctr, unsigned bi) {
    __syncthreads();
    if (threadIdx.x == 0) {
        __hip_atomic_fetch_add(gctr, 1u, __ATOMIC_RELAXED, __HIP_MEMORY_SCOPE_WORKGROUP);
        const unsigned target = 32u * bi;
        while (__hip_atomic_load(gctr, __ATOMIC_RELAXED, __HIP_MEMORY_SCOPE_AGENT) < target)
            __builtin_amdgcn_s_sleep(1);
    }
    __syncthreads();
    asm volatile("buffer_inv sc0" ::: "memory");
}

__global__ void __launch_bounds__(256, 1)
rnn_main(const float* __restrict__ x, const float* __restrict__ whx,
         const _Float16* __restrict__ W, const float* __restrict__ bh,
         const float* __restrict__ wph, const float* __restrict__ bp,
         _Float16* __restrict__ h0, _Float16* __restrict__ h1,
         unsigned* __restrict__ ctr, float* __restrict__ out)
{
    // 128 KiB: pinned W cols, FRAGMENT-MAJOR: 2 col-tiles x 64 ksteps x 64 lanes x 16B.
    // slot(tile,ks,lane) holds exactly the 16B MFMA B-fragment lane needs:
    //   W[colbase + tile*16 + (lane&15)][ks*32 + (lane>>4)*8 .. +8]
    // K-loop reads are lane-linear (addr = base + lane*16) -> zero bank conflicts.
    __shared__ uint4 lds4[8192];
    __shared__ unsigned s_mslot;
    char* lds = (char*)lds4;

    const int tid = threadIdx.x;

    // physical XCD id -> group; grab a member slot (exactly 32 WGs per XCD:
    // 128KiB LDS forces 1 WG/CU, cooperative launch fills all 256 CUs)
    int xcc;
    asm volatile("s_getreg_b32 %0, hwreg(HW_REG_XCC_ID)" : "=s"(xcc));
    const int g = xcc & 7;
    unsigned* gctr  = ctr + g * 64;          // barrier counter (256B padded)
    unsigned* alloc = ctr + 512 + g * 64;    // member allocator
    if (tid == 0)
        s_mslot = __hip_atomic_fetch_add(alloc, 1u, __ATOMIC_RELAXED, __HIP_MEMORY_SCOPE_WORKGROUP);
    __syncthreads();
    const int m = (int)s_mslot;              // 0..31
    const int rowbase = g * 32;              // group owns batch rows [rowbase,+32)
    const int colbase = m * 64;              // member owns hidden cols [colbase,+64)

    const int lane = tid & 63;
    const int w    = tid >> 6;               // wave 0..3
    const int wm   = w & 1;                  // M-half
    const int wn   = w >> 1;                 // 0: LDS-pinned cols, 1: streamed cols

    // ---- pin W cols [colbase, colbase+32) into LDS, fragment-major ----
    for (int s = tid; s < 8192; s += 256) {
        const int tile = s >> 12;
        const int ks   = (s >> 6) & 63;
        const int ln   = s & 63;
        const int col  = colbase + tile * 16 + (ln & 15);
        const int k0   = ks * 32 + (ln >> 4) * 8;
        const uint4 v = *(const uint4*)(W + (size_t)col * HID + k0);
        *(uint4*)(lds + s * 16) = v;
    }

    // ---- step 0: h = tanh(x[:,0]*whx + bh) (h_prev = 0, no GEMM) ----
    for (int i = tid; i < 32 * 64; i += 256) {
        const int r = i >> 6, c = i & 63;
        const int b = rowbase + r, j = colbase + c;
        h0[(size_t)b * HID + j] = (_Float16)fast_tanh(x[(size_t)b * SEQL] * whx[j] + bh[j]);
    }

    group_barrier(gctr, 1u);

    // per-lane epilogue constants (C/D layout: col=lane&15, row=(lane>>4)*4+r)
    const int c0 = colbase + wn * 32 + (lane & 15);
    const int c1 = c0 + 16;
    const float wx0 = whx[c0], wx1 = whx[c1];
    const float bb0 = bh[c0],  bb1 = bh[c1];
    const int arow = rowbase + wm * 16 + (lane & 15);   // A-operand row
    const int kq   = (lane >> 4) * 8;                   // per-lane k offset (halves)

    for (int t = 1; t < SEQL; ++t) {
        const _Float16* hs = (t & 1) ? h0 : h1;
        _Float16*       hd = (t & 1) ? h1 : h0;
        const _Float16* ap = hs + (size_t)arow * HID + kq;

        f32x4 a00 = {0.f,0.f,0.f,0.f}, a01 = a00, a10 = a00, a11 = a00;

        if (wn == 0) {
            // B from pinned LDS, lane-linear fragment reads
            const char* bb = lds + lane * 16;
            #pragma unroll 4
            for (int i = 0; i < 32; ++i) {
                const f16x8 a0 = *(const f16x8*)(ap + i * 64);
                const f16x8 a1 = *(const f16x8*)(ap + i * 64 + 32);
                const f16x8 p00 = *(const f16x8*)(bb + (2 * i) * 1024);
                const f16x8 p01 = *(const f16x8*)(bb + (2 * i + 1) * 1024);
                const f16x8 p10 = *(const f16x8*)(bb + 65536 + (2 * i) * 1024);
                const f16x8 p11 = *(const f16x8*)(bb + 65536 + (2 * i + 1) * 1024);
                a00 = __builtin_amdgcn_mfma_f32_16x16x32_f16(a0, p00, a00, 0, 0, 0);
                a10 = __builtin_amdgcn_mfma_f32_16x16x32_f16(a0, p10, a10, 0, 0, 0);
                a01 = __builtin_amdgcn_mfma_f32_16x16x32_f16(a1, p01, a01, 0, 0, 0);
                a11 = __builtin_amdgcn_mfma_f32_16x16x32_f16(a1, p11, a11, 0, 0, 0);
            }
        } else {
            // B streamed from W (cols colbase+32..+64), L2-resident
            const _Float16* q0 = W + (size_t)(colbase + 32 + (lane & 15)) * HID + kq;
            const _Float16* q1 = q0 + (size_t)16 * HID;
            #pragma unroll 4
            for (int i = 0; i < 32; ++i) {
                const int kk = i * 64;
                const f16x8 a0 = *(const f16x8*)(ap + kk);
                const f16x8 a1 = *(const f16x8*)(ap + kk + 32);
                const f16x8 p00 = *(const f16x8*)(q0 + kk);
                const f16x8 p10 = *(const f16x8*)(q1 + kk);
                const f16x8 p01 = *(const f16x8*)(q0 + kk + 32);
                const f16x8 p11 = *(const f16x8*)(q1 + kk + 32);
                a00 = __builtin_amdgcn_mfma_f32_16x16x32_f16(a0, p00, a00, 0, 0, 0);
                a10 = __builtin_amdgcn_mfma_f32_16x16x32_f16(a0, p10, a10, 0, 0, 0);
                a01 = __builtin_amdgcn_mfma_f32_16x16x32_f16(a1, p01, a01, 0, 0, 0);
                a11 = __builtin_amdgcn_mfma_f32_16x16x32_f16(a1, p11, a11, 0, 0, 0);
            }
        }

        // epilogue: sum K-parity accumulators, add x_t*whx + bh, tanh, store fp16
        const f32x4 s0 = a00 + a01;
        const f32x4 s1 = a10 + a11;
        const int rb = rowbase + wm * 16 + (lane >> 4) * 4;
        #pragma unroll
        for (int r = 0; r < 4; ++r) {
            const int br = rb + r;
            const float xv = x[(size_t)br * SEQL + t];
            hd[(size_t)br * HID + c0] = (_Float16)fast_tanh(s0[r] + xv * wx0 + bb0);
            hd[(size_t)br * HID + c1] = (_Float16)fast_tanh(s1[r] + xv * wx1 + bb1);
        }

        group_barrier(gctr, (unsigned)(t + 1));
    }

    // ---- projection: p = h_last @ wph.T + bp (h_last = h1; member m -> row rowbase+m) ----
    const int brow = rowbase + m;
    const _Float16* hp = h1 + (size_t)brow * HID + lane * 32;
    for (int c = w; c < NCLS; c += 4) {
        const float* wp = wph + (size_t)c * HID + lane * 32;
        float s = 0.f;
        #pragma unroll
        for (int i = 0; i < 32; ++i) s += (float)hp[i] * wp[i];
        #pragma unroll
        for (int off = 32; off >= 1; off >>= 1) s += __shfl_xor(s, off, 64);
        if (lane == 0) out[brow * NCLS + c] = s + bp[c];
    }
}

extern "C" void kernel_launch(void* const* d_in, const int* in_sizes, int n_in,
                              void* d_out, int out_size, void* d_ws, size_t ws_size,
                              hipStream_t stream) {
    const float* x   = (const float*)d_in[0];
    const float* whx = (const float*)d_in[1];
    const float* whh = (const float*)d_in[2];
    const float* bh  = (const float*)d_in[3];
    const float* wph = (const float*)d_in[4];
    const float* bp  = (const float*)d_in[5];
    float* out = (float*)d_out;

    char* ws = (char*)d_ws;
    _Float16* W16 = (_Float16*)ws;                         // 8 MiB  whh in fp16
    _Float16* h0  = (_Float16*)(ws + (size_t)(8u << 20));  // 1 MiB  h buffer A
    _Float16* h1  = (_Float16*)(ws + (size_t)(9u << 20));  // 1 MiB  h buffer B
    unsigned* ctr = (unsigned*)(ws + (size_t)(10u << 20)); // 4 KiB  barrier + member-alloc counters

    hipMemsetAsync(ctr, 0, 2 * 8 * 64 * sizeof(unsigned), stream);
    convert_w_kernel<<<dim3(4096), dim3(256), 0, stream>>>(whh, W16);

    void* args[] = { (void*)&x, (void*)&whx, (void*)&W16, (void*)&bh, (void*)&wph,
                     (void*)&bp, (void*)&h0, (void*)&h1, (void*)&ctr, (void*)&out };
    hipLaunchCooperativeKernel((const void*)rnn_main, dim3(256), dim3(256),
                               args, 0, stream);
}

// Round 4
// 6772.990 us; speedup vs baseline: 2.4079x; 1.4961x over previous
//
#include <hip/hip_runtime.h>

#define SEQL   512
#define HID    2048
#define NCLS   10

typedef _Float16 f16x8 __attribute__((ext_vector_type(8)));
typedef _Float16 f16x4 __attribute__((ext_vector_type(4)));
typedef float    f32x4 __attribute__((ext_vector_type(4)));
typedef unsigned uintx4 __attribute__((ext_vector_type(4)));

__device__ __forceinline__ float fast_tanh(float v) {
    float e = __expf(2.0f * v);
    return 1.0f - 2.0f / (e + 1.0f);
}

// whh fp32 -> fp16 (row-major [j][k] preserved)
__global__ void convert_w_kernel(const float* __restrict__ w, _Float16* __restrict__ o) {
    const int i = (blockIdx.x * 256 + threadIdx.x) * 4;
    const float4 v = *(const float4*)(w + i);
    f16x4 h;
    h[0] = (_Float16)v.x; h[1] = (_Float16)v.y;
    h[2] = (_Float16)v.z; h[3] = (_Float16)v.w;
    *(f16x4*)(o + i) = h;
}

// XCD-local 32-WG barrier — ROUND-2 PROVEN ENCODING, do not hand-roll cache bits.
//   arrive: workgroup-scope atomicAdd (executes at local L2)
//   spin:   agent-scope relaxed load (bypasses L1)
//   acquire: buffer_inv sc0 (invalidate this CU's L1; L2 untouched).
// L1 holds nothing valuable here (A/B in LDS/regs), so the inv is ~free.
__device__ __forceinline__ void group_barrier(unsigned* gctr, unsigned bi) {
    __syncthreads();
    if (threadIdx.x == 0) {
        __hip_atomic_fetch_add(gctr, 1u, __ATOMIC_RELAXED, __HIP_MEMORY_SCOPE_WORKGROUP);
        const unsigned target = 32u * bi;
        while (__hip_atomic_load(gctr, __ATOMIC_RELAXED, __HIP_MEMORY_SCOPE_AGENT) < target)
            __builtin_amdgcn_s_sleep(1);
    }
    __syncthreads();
    asm volatile("buffer_inv sc0" ::: "memory");
}

__global__ void __launch_bounds__(256, 1)
rnn_main(const float* __restrict__ x, const float* __restrict__ whx,
         const _Float16* __restrict__ W, const float* __restrict__ bh,
         const float* __restrict__ wph, const float* __restrict__ bp,
         _Float16* __restrict__ h0, _Float16* __restrict__ h1,
         unsigned* __restrict__ ctr, float* __restrict__ out)
{
    // 128 KiB pinned W (cols [colbase, colbase+32)), fragment-major:
    //   slot(tile,kst,lane) = W[colbase+tile*16+(lane&15)][kst*32+(lane>>4)*8 ..+8]
    __shared__ uint4 ldsW[8192];
    // 2 x 8 KiB double-buffered A slice (k=128), fragment-major:
    //   slot(wm,ks,lane) = h[rowbase+wm*16+(lane&15)][s*128+ks*32+(lane>>4)*8 ..+8]
    __shared__ uint4 ldsA[2][512];
    __shared__ unsigned s_mslot;

    const int tid = threadIdx.x;

    // physical XCD id -> group; member slot via allocator (32 WGs/XCD: 1 WG/CU)
    int xcc;
    asm volatile("s_getreg_b32 %0, hwreg(HW_REG_XCC_ID)" : "=s"(xcc));
    const int g = xcc & 7;
    unsigned* gctr  = ctr + g * 64;
    unsigned* alloc = ctr + 512 + g * 64;
    if (tid == 0)
        s_mslot = __hip_atomic_fetch_add(alloc, 1u, __ATOMIC_RELAXED, __HIP_MEMORY_SCOPE_WORKGROUP);
    __syncthreads();
    const int m = (int)s_mslot;              // 0..31
    const int rowbase = g * 32;
    const int colbase = m * 64;

    const int lane = tid & 63;
    const int w    = tid >> 6;               // wave 0..3, 16 cols each
                                             // w<2: B pinned in LDS; w>=2: B streamed

    // ---- pin W cols [colbase, colbase+32) into LDS, fragment-major ----
    for (int s = tid; s < 8192; s += 256) {
        const int tile = s >> 12;
        const int kst  = (s >> 6) & 63;
        const int ln   = s & 63;
        const int col  = colbase + tile * 16 + (ln & 15);
        const int k0   = kst * 32 + (ln >> 4) * 8;
        ldsW[s] = *(const uint4*)(W + (size_t)col * HID + k0);
    }

    // ---- step 0: h = tanh(x[:,0]*whx + bh) ----
    for (int i = tid; i < 32 * 64; i += 256) {
        const int r = i >> 6, c = i & 63;
        const int b = rowbase + r, j = colbase + c;
        h0[(size_t)b * HID + j] = (_Float16)fast_tanh(x[(size_t)b * SEQL] * whx[j] + bh[j]);
    }
    group_barrier(gctr, 1u);

    // per-thread staging source (writes slots tid (wm=0) and tid+256 (wm=1))
    const int srow0 = rowbase + (tid & 15);
    const int srow1 = srow0 + 16;
    const int skoff = ((tid >> 6) & 3) * 32 + ((tid >> 4) & 3) * 8;

    // per-wave constants
    const int cc = colbase + w * 16 + (lane & 15);      // C/D col = lane&15
    const float wxc = whx[cc], bbc = bh[cc];
    const _Float16* qb = W + (size_t)cc * HID + (lane >> 4) * 8;  // streamed B base
    const uint4* wb = &ldsW[(w & 1) * 4096 + lane];               // pinned B base
    const int rb0 = rowbase + (lane >> 4) * 4;          // epilogue rows (wm=0)

    f16x8 Bf[32];   // streaming waves: half-step of B fragments in registers

    for (int t = 1; t < SEQL; ++t) {
        const _Float16* hs = (t & 1) ? h0 : h1;
        _Float16*       hd = (t & 1) ? h1 : h0;
        const _Float16* sp0 = hs + (size_t)srow0 * HID + skoff;
        const _Float16* sp1 = hs + (size_t)srow1 * HID + skoff;

        // prologue: stage A slice 0
        {
            const uintx4 r0 = *(const uintx4*)sp0;
            const uintx4 r1 = *(const uintx4*)sp1;
            *(uintx4*)&ldsA[0][tid]       = r0;
            *(uintx4*)&ldsA[0][tid + 256] = r1;
        }
        __syncthreads();

        f32x4 acc00 = {0.f,0.f,0.f,0.f}, acc01 = acc00, acc10 = acc00, acc11 = acc00;

        for (int half = 0; half < 2; ++half) {
            if (w >= 2) {   // batch-load 32 B fragments (8 slices) into registers
                #pragma unroll
                for (int i = 0; i < 32; ++i)
                    Bf[i] = *(const f16x8*)(qb + (half * 32 + i) * 32);
            }
            #pragma unroll
            for (int ss = 0; ss < 8; ++ss) {
                const int s = half * 8 + ss;
                const int p = s & 1;
                uintx4 r0, r1;
                if (s < 15) {   // issue next A slice's loads before the MFMAs
                    r0 = *(const uintx4*)(sp0 + (s + 1) * 128);
                    r1 = *(const uintx4*)(sp1 + (s + 1) * 128);
                }
                const uint4* Ab = &ldsA[p][0];
                if (w < 2) {
                    #pragma unroll
                    for (int ks = 0; ks < 4; ++ks) {
                        const f16x8 a0 = *(const f16x8*)&Ab[ks * 64 + lane];
                        const f16x8 a1 = *(const f16x8*)&Ab[256 + ks * 64 + lane];
                        const f16x8 b  = *(const f16x8*)&wb[(s * 4 + ks) * 64];
                        if (ks & 1) {
                            acc01 = __builtin_amdgcn_mfma_f32_16x16x32_f16(a0, b, acc01, 0, 0, 0);
                            acc11 = __builtin_amdgcn_mfma_f32_16x16x32_f16(a1, b, acc11, 0, 0, 0);
                        } else {
                            acc00 = __builtin_amdgcn_mfma_f32_16x16x32_f16(a0, b, acc00, 0, 0, 0);
                            acc10 = __builtin_amdgcn_mfma_f32_16x16x32_f16(a1, b, acc10, 0, 0, 0);
                        }
                    }
                } else {
                    #pragma unroll
                    for (int ks = 0; ks < 4; ++ks) {
                        const f16x8 a0 = *(const f16x8*)&Ab[ks * 64 + lane];
                        const f16x8 a1 = *(const f16x8*)&Ab[256 + ks * 64 + lane];
                        const f16x8 b  = Bf[ss * 4 + ks];
                        if (ks & 1) {
                            acc01 = __builtin_amdgcn_mfma_f32_16x16x32_f16(a0, b, acc01, 0, 0, 0);
                            acc11 = __builtin_amdgcn_mfma_f32_16x16x32_f16(a1, b, acc11, 0, 0, 0);
                        } else {
                            acc00 = __builtin_amdgcn_mfma_f32_16x16x32_f16(a0, b, acc00, 0, 0, 0);
                            acc10 = __builtin_amdgcn_mfma_f32_16x16x32_f16(a1, b, acc10, 0, 0, 0);
                        }
                    }
                }
                if (s < 15) {   // write next slice (other buffer: no race with readers of p)
                    *(uintx4*)&ldsA[p ^ 1][tid]       = r0;
                    *(uintx4*)&ldsA[p ^ 1][tid + 256] = r1;
                }
                __syncthreads();
            }
        }

        // epilogue: sum k-parity accs, add x_t*whx + bh, tanh, store fp16
        const f32x4 s0 = acc00 + acc01;
        const f32x4 s1 = acc10 + acc11;
        #pragma unroll
        for (int r = 0; r < 4; ++r) {
            const int br0 = rb0 + r;
            hd[(size_t)br0 * HID + cc] =
                (_Float16)fast_tanh(s0[r] + x[(size_t)br0 * SEQL + t] * wxc + bbc);
            const int br1 = br0 + 16;
            hd[(size_t)br1 * HID + cc] =
                (_Float16)fast_tanh(s1[r] + x[(size_t)br1 * SEQL + t] * wxc + bbc);
        }

        group_barrier(gctr, (unsigned)(t + 1));
    }

    // ---- projection: p = h_last @ wph.T + bp (member m -> row rowbase+m) ----
    const int brow = rowbase + m;
    const _Float16* hp = h1 + (size_t)brow * HID + lane * 32;
    for (int c = w; c < NCLS; c += 4) {
        const float* wp = wph + (size_t)c * HID + lane * 32;
        float ssum = 0.f;
        #pragma unroll
        for (int i = 0; i < 32; ++i) ssum += (float)hp[i] * wp[i];
        #pragma unroll
        for (int off = 32; off >= 1; off >>= 1) ssum += __shfl_xor(ssum, off, 64);
        if (lane == 0) out[brow * NCLS + c] = ssum + bp[c];
    }
}

extern "C" void kernel_launch(void* const* d_in, const int* in_sizes, int n_in,
                              void* d_out, int out_size, void* d_ws, size_t ws_size,
                              hipStream_t stream) {
    const float* x   = (const float*)d_in[0];
    const float* whx = (const float*)d_in[1];
    const float* whh = (const float*)d_in[2];
    const float* bh  = (const float*)d_in[3];
    const float* wph = (const float*)d_in[4];
    const float* bp  = (const float*)d_in[5];
    float* out = (float*)d_out;

    char* ws = (char*)d_ws;
    _Float16* W16 = (_Float16*)ws;                         // 8 MiB  whh fp16
    _Float16* h0  = (_Float16*)(ws + (size_t)(8u << 20));  // 1 MiB  h buffer A
    _Float16* h1  = (_Float16*)(ws + (size_t)(9u << 20));  // 1 MiB  h buffer B
    unsigned* ctr = (unsigned*)(ws + (size_t)(10u << 20)); // 4 KiB  counters

    hipMemsetAsync(ctr, 0, 2 * 8 * 64 * sizeof(unsigned), stream);
    convert_w_kernel<<<dim3(4096), dim3(256), 0, stream>>>(whh, W16);

    void* args[] = { (void*)&x, (void*)&whx, (void*)&W16, (void*)&bh, (void*)&wph,
                     (void*)&bp, (void*)&h0, (void*)&h1, (void*)&ctr, (void*)&out };
    hipLaunchCooperativeKernel((const void*)rnn_main, dim3(256), dim3(256),
                               args, 0, stream);
}